// Round 3
// baseline (302.004 us; speedup 1.0000x reference)
//
#include <hip/hip_runtime.h>
#include <hip/hip_cooperative_groups.h>
#include <math.h>

namespace cg = cooperative_groups;

// Problem constants
#define BB 2
#define LL 128
#define HH 768
#define H2 1536          // 2*H
#define CC 6
#define NTOK (BB * LL)   // 256
#define TOKSZ (NTOK * CC)

// Workspace layout (float offsets)
#define WFC_OFF   0          // Wfc = Wf @ cls_w   (1536 x 6)
#define WFWFC_OFF 9216       // WfWfc = Wf @ Wfc   (1536 x 6)
#define SM_OFF    18432      // K1=0 M3=36 M4=72 K2=108 M3f=144 M4f=180 d1=216 dbfc=222 (Cfin=234, by P4)
#define TOK_OFF   18672      // 6 arrays of TOKSZ: 0:p 1:q 2:r1 3:r2 4:s1 5:s2
#define AF_OFF (TOK_OFF + 6 * TOKSZ)
#define BF_OFF (TOK_OFF + 7 * TOKSZ)

// One cooperative kernel, 256 blocks x 256 threads (1 block/CU -> co-resident).
// P1: Wfc rows + dots vs cls_w          | grid.sync
// P2: WfWfc rows + dots vs Wfc + p/q/r1/r2 tokens | grid.sync
// P3: s1/s2 tokens                      | grid.sync
// P4: plane (2 blocks, shfl-scan pooling; assumes BINARY attention mask) | grid.sync
// P5: out[b,i,j,c] = Af[b,i,c]+Bf[b,j,c]+Cfin[c]  (1 (b,i)-row per block)
__global__ __launch_bounds__(256) void coop_all(
    const float* __restrict__ hidden, const float* __restrict__ mask_in,
    const float* __restrict__ cls_w, const float* __restrict__ cls_b,
    const float* __restrict__ feat_w, const float* __restrict__ feat_b,
    float* __restrict__ ws, float* __restrict__ out)
{
    cg::grid_group grid = cg::this_grid();
    const int blk = blockIdx.x, tid = threadIdx.x;
    const int wave = tid >> 6, lane = tid & 63;

    __shared__ float sredm[4][4][CC];   // [wave][group][c] block reductions
    __shared__ float sred1[4];
    __shared__ float sm_sh[240];
    __shared__ float cb_sh[CC];
    __shared__ float xw[2][CC + 1];     // cross-wave scan merge (6 vals + mask)
    __shared__ float stage[768 + 2 * CC];

    // ------------------------- P1: Wfc + dots vs cls_w -------------------------
    for (int task = blk; task < H2 + 114; task += 256) {
        if (task < H2) {
            float acc[CC] = {};
            const float* arow = feat_w + (size_t)task * H2;
            for (int r = tid; r < H2; r += 256) {
                float w = arow[r];
                const float* brow = cls_w + r * CC;
#pragma unroll
                for (int c = 0; c < CC; ++c) acc[c] += w * brow[c];
            }
#pragma unroll
            for (int c = 0; c < CC; ++c)
#pragma unroll
                for (int off = 32; off > 0; off >>= 1) acc[c] += __shfl_down(acc[c], off, 64);
            if (lane == 0)
#pragma unroll
                for (int c = 0; c < CC; ++c) sredm[wave][0][c] = acc[c];
            __syncthreads();
            if (tid < CC)
                ws[WFC_OFF + task * CC + tid] =
                    sredm[0][0][tid] + sredm[1][0][tid] + sredm[2][0][tid] + sredm[3][0][tid];
            __syncthreads();
        } else {
            int dt = task - H2;   // 0..113
            const float* va;
            int c, outIdx;
            bool add_clsb = false;
            if (dt < 108) {
                int m = dt / 36, e = dt % 36, cp = e / CC;
                c = e % CC;
                int row = (m == 0) ? (H2 + 2 * CC) : ((m == 1) ? H2 : (H2 + CC)); // K1:W5 M3:W3 M4:W4
                va = feat_w + (size_t)(row + cp) * H2;
                outIdx = m * 36 + e;
            } else {
                c = dt - 108;
                va = feat_b;
                outIdx = 216 + c;
                add_clsb = true;
            }
            float acc = 0.f;
            for (int r = tid; r < H2; r += 256) acc += va[r] * cls_w[r * CC + c];
#pragma unroll
            for (int off = 32; off > 0; off >>= 1) acc += __shfl_down(acc, off, 64);
            if (lane == 0) sred1[wave] = acc;
            __syncthreads();
            if (tid == 0) {
                float v = sred1[0] + sred1[1] + sred1[2] + sred1[3];
                if (add_clsb) v += cls_b[c];
                ws[SM_OFF + outIdx] = v;
            }
            __syncthreads();
        }
    }
    __threadfence();
    grid.sync();

    // --------------- P2: WfWfc + dots vs Wfc + token p,q,r1,r2 ---------------
    {
        const float* Wfc = ws + WFC_OFF;
        for (int task = blk; task < H2 + 114 + NTOK; task += 256) {
            if (task < H2) {
                float acc[CC] = {};
                const float* arow = feat_w + (size_t)task * H2;
                for (int r = tid; r < H2; r += 256) {
                    float w = arow[r];
                    const float* brow = Wfc + r * CC;
#pragma unroll
                    for (int c = 0; c < CC; ++c) acc[c] += w * brow[c];
                }
#pragma unroll
                for (int c = 0; c < CC; ++c)
#pragma unroll
                    for (int off = 32; off > 0; off >>= 1) acc[c] += __shfl_down(acc[c], off, 64);
                if (lane == 0)
#pragma unroll
                    for (int c = 0; c < CC; ++c) sredm[wave][0][c] = acc[c];
                __syncthreads();
                if (tid < CC)
                    ws[WFWFC_OFF + task * CC + tid] =
                        sredm[0][0][tid] + sredm[1][0][tid] + sredm[2][0][tid] + sredm[3][0][tid];
                __syncthreads();
            } else if (task < H2 + 114) {
                int dt = task - H2;
                const float* va;
                int c, outIdx;
                if (dt < 108) {
                    int m = dt / 36, e = dt % 36, cp = e / CC;
                    c = e % CC;
                    int row = (m == 0) ? (H2 + 2 * CC) : ((m == 1) ? H2 : (H2 + CC)); // K2 M3f M4f
                    va = feat_w + (size_t)(row + cp) * H2;
                    outIdx = (m + 3) * 36 + e;
                } else {
                    c = dt - 108;
                    va = feat_b;
                    outIdx = 222 + c;
                }
                float acc = 0.f;
                for (int r = tid; r < H2; r += 256) acc += va[r] * Wfc[r * CC + c];
#pragma unroll
                for (int off = 32; off > 0; off >>= 1) acc += __shfl_down(acc, off, 64);
                if (lane == 0) sred1[wave] = acc;
                __syncthreads();
                if (tid == 0) ws[SM_OFF + outIdx] = sred1[0] + sred1[1] + sred1[2] + sred1[3];
                __syncthreads();
            } else {
                int tok = task - (H2 + 114);
                float acc[4][CC] = {};
                const float* hrow = hidden + (size_t)tok * HH;
                for (int k = tid; k < HH; k += 256) {
                    float hk = hrow[k];
                    const float* c0 = cls_w + k * CC;
                    const float* c1 = cls_w + (HH + k) * CC;
                    const float* w0 = Wfc + k * CC;
                    const float* w1 = Wfc + (HH + k) * CC;
#pragma unroll
                    for (int c = 0; c < CC; ++c) {
                        acc[0][c] += hk * c0[c];
                        acc[1][c] += hk * c1[c];
                        acc[2][c] += hk * w0[c];
                        acc[3][c] += hk * w1[c];
                    }
                }
#pragma unroll
                for (int g = 0; g < 4; ++g)
#pragma unroll
                    for (int c = 0; c < CC; ++c)
#pragma unroll
                        for (int off = 32; off > 0; off >>= 1) acc[g][c] += __shfl_down(acc[g][c], off, 64);
                if (lane == 0)
#pragma unroll
                    for (int g = 0; g < 4; ++g)
#pragma unroll
                        for (int c = 0; c < CC; ++c) sredm[wave][g][c] = acc[g][c];
                __syncthreads();
                if (tid < 24) {
                    int g = tid / CC, c = tid % CC;
                    ws[TOK_OFF + g * TOKSZ + tok * CC + c] =
                        sredm[0][g][c] + sredm[1][g][c] + sredm[2][g][c] + sredm[3][g][c];
                }
                __syncthreads();
            }
        }
    }
    __threadfence();
    grid.sync();

    // ------------------------- P3: token s1,s2 (1 tok/block) -------------------------
    {
        const float* Wf2 = ws + WFWFC_OFF;
        int tok = blk;  // grid = 256 = NTOK
        float acc[2][CC] = {};
        const float* hrow = hidden + (size_t)tok * HH;
        for (int k = tid; k < HH; k += 256) {
            float hk = hrow[k];
            const float* v0 = Wf2 + k * CC;
            const float* v1 = Wf2 + (HH + k) * CC;
#pragma unroll
            for (int c = 0; c < CC; ++c) {
                acc[0][c] += hk * v0[c];
                acc[1][c] += hk * v1[c];
            }
        }
#pragma unroll
        for (int g = 0; g < 2; ++g)
#pragma unroll
            for (int c = 0; c < CC; ++c)
#pragma unroll
                for (int off = 32; off > 0; off >>= 1) acc[g][c] += __shfl_down(acc[g][c], off, 64);
        if (lane == 0)
#pragma unroll
            for (int g = 0; g < 2; ++g)
#pragma unroll
                for (int c = 0; c < CC; ++c) sredm[wave][g][c] = acc[g][c];
        __syncthreads();
        if (tid < 12) {
            int g = tid / CC, c = tid % CC;
            ws[TOK_OFF + (4 + g) * TOKSZ + tok * CC + c] =
                sredm[0][g][c] + sredm[1][g][c] + sredm[2][g][c] + sredm[3][g][c];
        }
        __syncthreads();
    }
    __threadfence();
    grid.sync();

    // ------------------------- P4: plane (blocks 0,1) -------------------------
    // Pooling via prefix/suffix max scans; EXACT for binary {0,1} masks
    // (fmax is associative, so this is a pure reassociation of the R1 loop).
    if (blk < BB) {
        const int b = blk;
        if (tid < 240) sm_sh[tid] = ws[SM_OFF + tid];
        if (tid < CC) cb_sh[tid] = cls_b[tid];
        __syncthreads();

        const int t = tid;           // valid when tid < 128
        float p[CC], q[CC], al[CC], be[CC], pool0v[CC], pool1v[CC], gam[CC];
        float prefV[CC], sufV[CC], prefm = 1.f, sufm = 1.f, m_t = 0.f;
        bool mt = false;

        if (tid < LL) {
            m_t = mask_in[b * LL + t];
            mt = (m_t != 0.f);
#pragma unroll
            for (int c = 0; c < CC; ++c) {
                p[c] = ws[TOK_OFF + 0 * TOKSZ + (b * LL + t) * CC + c];
                q[c] = ws[TOK_OFF + 1 * TOKSZ + (b * LL + t) * CC + c];
            }
#pragma unroll
            for (int c = 0; c < CC; ++c) {
                float g = sm_sh[216 + c];
                for (int cp = 0; cp < CC; ++cp) g += cb_sh[cp] * sm_sh[cp * CC + c];
                gam[c] = g;
            }
#pragma unroll
            for (int c = 0; c < CC; ++c) {
                prefV[c] = mt ? p[c] : -INFINITY;
                sufV[c] = mt ? q[c] : -INFINITY;
            }
            prefm = m_t;
            sufm = m_t;
            // intra-wave scans
#pragma unroll
            for (int off = 1; off < 64; off <<= 1) {
#pragma unroll
                for (int c = 0; c < CC; ++c) {
                    float v = __shfl_up(prefV[c], off, 64);
                    if (lane >= off) prefV[c] = fmaxf(prefV[c], v);
                    float u = __shfl_down(sufV[c], off, 64);
                    if (lane < 64 - off) sufV[c] = fmaxf(sufV[c], u);
                }
                float vm = __shfl_up(prefm, off, 64);
                if (lane >= off) prefm = fminf(prefm, vm);
                float um = __shfl_down(sufm, off, 64);
                if (lane < 64 - off) sufm = fminf(sufm, um);
            }
            if (lane == 63 && wave == 0) {
#pragma unroll
                for (int c = 0; c < CC; ++c) xw[0][c] = prefV[c];
                xw[0][CC] = prefm;
            }
            if (lane == 0 && wave == 1) {
#pragma unroll
                for (int c = 0; c < CC; ++c) xw[1][c] = sufV[c];
                xw[1][CC] = sufm;
            }
        }
        __syncthreads();
        if (tid < LL) {
            if (wave == 1) {
#pragma unroll
                for (int c = 0; c < CC; ++c) prefV[c] = fmaxf(prefV[c], xw[0][c]);
                prefm = fminf(prefm, xw[0][CC]);
            } else {
#pragma unroll
                for (int c = 0; c < CC; ++c) sufV[c] = fmaxf(sufV[c], xw[1][c]);
                sufm = fminf(sufm, xw[1][CC]);
            }
            bool colz = (t < LL - 1) || (prefm == 0.f);
            bool rowz = (t > 0) || (sufm == 0.f);
#pragma unroll
            for (int c = 0; c < CC; ++c) {
                float cm = 0.f, rm = 0.f;
                if (mt) {
                    cm = prefV[c] + q[c] + cb_sh[c];
                    if (colz) cm = fmaxf(cm, 0.f);
                    rm = p[c] + sufV[c] + cb_sh[c];
                    if (rowz) rm = fmaxf(rm, 0.f);
                }
                pool0v[c] = fmaxf(cm, rm);
            }
            // alpha/beta
#pragma unroll
            for (int c = 0; c < CC; ++c) {
                al[c] = ws[TOK_OFF + 2 * TOKSZ + (b * LL + t) * CC + c];
                be[c] = ws[TOK_OFF + 3 * TOKSZ + (b * LL + t) * CC + c];
            }
#pragma unroll
            for (int c = 0; c < CC; ++c)
                for (int cp = 0; cp < CC; ++cp) {
                    al[c] += pool0v[cp] * sm_sh[36 + cp * CC + c] + p[cp] * sm_sh[cp * CC + c];
                    be[c] += pool0v[cp] * sm_sh[72 + cp * CC + c] + q[cp] * sm_sh[cp * CC + c];
                }
            // round-2 scan inputs
#pragma unroll
            for (int c = 0; c < CC; ++c) {
                prefV[c] = mt ? al[c] : -INFINITY;
                sufV[c] = mt ? be[c] : -INFINITY;
            }
#pragma unroll
            for (int off = 1; off < 64; off <<= 1) {
#pragma unroll
                for (int c = 0; c < CC; ++c) {
                    float v = __shfl_up(prefV[c], off, 64);
                    if (lane >= off) prefV[c] = fmaxf(prefV[c], v);
                    float u = __shfl_down(sufV[c], off, 64);
                    if (lane < 64 - off) sufV[c] = fmaxf(sufV[c], u);
                }
            }
        }
        __syncthreads();   // xw reuse boundary
        if (tid < LL) {
            if (lane == 63 && wave == 0)
#pragma unroll
                for (int c = 0; c < CC; ++c) xw[0][c] = prefV[c];
            if (lane == 0 && wave == 1)
#pragma unroll
                for (int c = 0; c < CC; ++c) xw[1][c] = sufV[c];
        }
        __syncthreads();
        if (tid < LL) {
            if (wave == 1)
#pragma unroll
                for (int c = 0; c < CC; ++c) prefV[c] = fmaxf(prefV[c], xw[0][c]);
            else
#pragma unroll
                for (int c = 0; c < CC; ++c) sufV[c] = fmaxf(sufV[c], xw[1][c]);
            bool colz = (t < LL - 1) || (prefm == 0.f);
            bool rowz = (t > 0) || (sufm == 0.f);
#pragma unroll
            for (int c = 0; c < CC; ++c) {
                float cm = 0.f, rm = 0.f;
                if (mt) {
                    cm = prefV[c] + be[c] + gam[c];
                    if (colz) cm = fmaxf(cm, 0.f);
                    rm = al[c] + sufV[c] + gam[c];
                    if (rowz) rm = fmaxf(rm, 0.f);
                }
                pool1v[c] = fmaxf(cm, rm);
            }
            // Afin / Bfin
#pragma unroll
            for (int c = 0; c < CC; ++c) {
                float A = ws[TOK_OFF + 4 * TOKSZ + (b * LL + t) * CC + c];
                float Bv = ws[TOK_OFF + 5 * TOKSZ + (b * LL + t) * CC + c];
                for (int cp = 0; cp < CC; ++cp) {
                    A += pool0v[cp] * sm_sh[144 + cp * CC + c] + pool1v[cp] * sm_sh[36 + cp * CC + c]
                       + p[cp] * sm_sh[108 + cp * CC + c] + al[cp] * sm_sh[cp * CC + c];
                    Bv += pool0v[cp] * sm_sh[180 + cp * CC + c] + pool1v[cp] * sm_sh[72 + cp * CC + c]
                        + q[cp] * sm_sh[108 + cp * CC + c] + be[cp] * sm_sh[cp * CC + c];
                }
                ws[AF_OFF + (b * LL + t) * CC + c] = A;
                ws[BF_OFF + (b * LL + t) * CC + c] = Bv;
            }
            // Cfin (block 0 only): dbfc + d1 + cls_b@K2 + gamma@K1
            if (b == 0 && tid < CC) {
                float f = sm_sh[222 + tid] + sm_sh[216 + tid];
                for (int cp = 0; cp < CC; ++cp)
                    f += cb_sh[cp] * sm_sh[108 + cp * CC + tid] + gam[cp] * sm_sh[cp * CC + tid];
                ws[SM_OFF + 234 + tid] = f;
            }
        }
    }
    __threadfence();
    grid.sync();

    // ------------------------- P5: output, 1 (b,i)-row per block -------------------------
    {
        const int b = blk >> 7, i = blk & 127;
        for (int v = tid; v < LL * CC; v += 256) stage[v] = ws[BF_OFF + b * LL * CC + v];
        if (tid < CC) stage[768 + tid] = ws[AF_OFF + (b * LL + i) * CC + tid];
        if (tid < CC) stage[768 + CC + tid] = ws[SM_OFF + 234 + tid];
        __syncthreads();
        if (tid < (LL * CC) / 4) {
            int r = tid * 4;
            float4 o;
            float* op = &o.x;
#pragma unroll
            for (int k = 0; k < 4; ++k) {
                int idx = r + k;
                int c = idx % CC;
                op[k] = stage[768 + c] + stage[idx] + stage[768 + CC + c];
            }
            *(float4*)(out + ((size_t)(b * LL + i)) * (LL * CC) + r) = o;
        }
    }
}

// ---------------------------------------------------------------------------
extern "C" void kernel_launch(void* const* d_in, const int* in_sizes, int n_in,
                              void* d_out, int out_size, void* d_ws, size_t ws_size,
                              hipStream_t stream) {
    const float* hidden = (const float*)d_in[0];          // (2,128,768)
    const float* attention_mask = (const float*)d_in[1];  // (2,128)
    const float* cls_w = (const float*)d_in[2];           // (1536,6)
    const float* cls_b = (const float*)d_in[3];           // (6,)
    const float* feat_w = (const float*)d_in[4];          // (1554,1536)
    const float* feat_b = (const float*)d_in[5];          // (1536,)
    // d_in[6] = nhops, fixed at 2
    float* out = (float*)d_out;
    float* ws = (float*)d_ws;

    void* args[] = {(void*)&hidden, (void*)&attention_mask, (void*)&cls_w, (void*)&cls_b,
                    (void*)&feat_w, (void*)&feat_b, (void*)&ws, (void*)&out};
    hipLaunchCooperativeKernel((void*)coop_all, dim3(256), dim3(256), args, 0, stream);
}

// Round 4
// 123.279 us; speedup vs baseline: 2.4498x; 2.4498x over previous
//
#include <hip/hip_runtime.h>
#include <math.h>

// Problem constants
#define BB 2
#define LL 128
#define HH 768
#define H2 1536          // 2*H
#define CC 6
#define NTOK (BB * LL)   // 256
#define TOKSZ (NTOK * CC)

// Workspace layout (float offsets)
#define WFC_OFF   0          // Wfc = Wf @ cls_w   (1536 x 6)
#define WFWFC_OFF 9216       // WfWfc = Wf @ Wfc   (1536 x 6)
#define SM_OFF    18432      // K1=0 M3=36 M4=72 K2=108 M3f=144 M4f=180 d1=216 dbfc=222
#define TOK_OFF   18672      // 4 arrays of TOKSZ: 0:p 1:q 2:r1 3:r2

// ---------------------------------------------------------------------------
// K1: blocks 0..1535   -> Wfc row k (feat_w row k @ cls_w)
//     blocks 1536..1649 -> 114 dot tasks vs cls_w (K1, M3, M4, d1)
// (validated in R2)
__global__ __launch_bounds__(256) void k1_wfc_dots(const float* __restrict__ feat_w,
                                                   const float* __restrict__ cls_w,
                                                   const float* __restrict__ cls_b,
                                                   const float* __restrict__ feat_b,
                                                   float* __restrict__ ws) {
    int blk = blockIdx.x, tid = threadIdx.x;
    int wave = tid >> 6, lane = tid & 63;
    if (blk < H2) {
        float acc[CC] = {};
        const float* arow = feat_w + (size_t)blk * H2;
        for (int r = tid; r < H2; r += 256) {
            float w = arow[r];
            const float* brow = cls_w + r * CC;
#pragma unroll
            for (int c = 0; c < CC; ++c) acc[c] += w * brow[c];
        }
#pragma unroll
        for (int c = 0; c < CC; ++c)
#pragma unroll
            for (int off = 32; off > 0; off >>= 1) acc[c] += __shfl_down(acc[c], off, 64);
        __shared__ float sred[4][CC];
        if (lane == 0)
#pragma unroll
            for (int c = 0; c < CC; ++c) sred[wave][c] = acc[c];
        __syncthreads();
        if (tid < CC)
            ws[WFC_OFF + blk * CC + tid] = sred[0][tid] + sred[1][tid] + sred[2][tid] + sred[3][tid];
    } else {
        int task = blk - H2;   // 0..113
        const float* va;
        int c, outIdx;
        bool add_clsb = false;
        if (task < 108) {
            int m = task / 36, e = task % 36, cp = e / CC;
            c = e % CC;
            int row = (m == 0) ? (H2 + 2 * CC) : ((m == 1) ? H2 : (H2 + CC)); // K1:W5 M3:W3 M4:W4
            va = feat_w + (size_t)(row + cp) * H2;
            outIdx = m * 36 + e;
        } else {
            c = task - 108;
            va = feat_b;
            outIdx = 216 + c;
            add_clsb = true;
        }
        float acc = 0.f;
        for (int r = tid; r < H2; r += 256) acc += va[r] * cls_w[r * CC + c];
#pragma unroll
        for (int off = 32; off > 0; off >>= 1) acc += __shfl_down(acc, off, 64);
        __shared__ float sred1[4];
        if (lane == 0) sred1[wave] = acc;
        __syncthreads();
        if (tid == 0) {
            float v = sred1[0] + sred1[1] + sred1[2] + sred1[3];
            if (add_clsb) v += cls_b[c];
            ws[SM_OFF + outIdx] = v;
        }
    }
}

// ---------------------------------------------------------------------------
// K2: blocks 0..1535    -> WfWfc row k (feat_w row k @ Wfc)
//     blocks 1536..1649 -> 114 dot tasks vs Wfc (K2, M3f, M4f, dbfc)
//     blocks 1650..1905 -> token projections p,q,r1,r2 for token (blk-1650)
// (validated in R2)
__global__ __launch_bounds__(256) void k2_wfwfc_dots_tok(const float* __restrict__ feat_w,
                                                         const float* __restrict__ cls_w,
                                                         const float* __restrict__ feat_b,
                                                         const float* __restrict__ hidden,
                                                         float* __restrict__ ws) {
    const float* Wfc = ws + WFC_OFF;
    int blk = blockIdx.x, tid = threadIdx.x;
    int wave = tid >> 6, lane = tid & 63;
    if (blk < H2) {
        float acc[CC] = {};
        const float* arow = feat_w + (size_t)blk * H2;
        for (int r = tid; r < H2; r += 256) {
            float w = arow[r];
            const float* brow = Wfc + r * CC;
#pragma unroll
            for (int c = 0; c < CC; ++c) acc[c] += w * brow[c];
        }
#pragma unroll
        for (int c = 0; c < CC; ++c)
#pragma unroll
            for (int off = 32; off > 0; off >>= 1) acc[c] += __shfl_down(acc[c], off, 64);
        __shared__ float sred[4][CC];
        if (lane == 0)
#pragma unroll
            for (int c = 0; c < CC; ++c) sred[wave][c] = acc[c];
        __syncthreads();
        if (tid < CC)
            ws[WFWFC_OFF + blk * CC + tid] = sred[0][tid] + sred[1][tid] + sred[2][tid] + sred[3][tid];
    } else if (blk < H2 + 114) {
        int task = blk - H2;
        const float* va;
        int c, outIdx;
        if (task < 108) {
            int m = task / 36, e = task % 36, cp = e / CC;
            c = e % CC;
            int row = (m == 0) ? (H2 + 2 * CC) : ((m == 1) ? H2 : (H2 + CC)); // K2 M3f M4f
            va = feat_w + (size_t)(row + cp) * H2;
            outIdx = (m + 3) * 36 + e;  // 108 / 144 / 180
        } else {
            c = task - 108;
            va = feat_b;
            outIdx = 222 + c;
        }
        float acc = 0.f;
        for (int r = tid; r < H2; r += 256) acc += va[r] * Wfc[r * CC + c];
#pragma unroll
        for (int off = 32; off > 0; off >>= 1) acc += __shfl_down(acc, off, 64);
        __shared__ float sred1[4];
        if (lane == 0) sred1[wave] = acc;
        __syncthreads();
        if (tid == 0) ws[SM_OFF + outIdx] = sred1[0] + sred1[1] + sred1[2] + sred1[3];
    } else {
        int tok = blk - (H2 + 114);
        float acc[4][CC] = {};
        const float* hrow = hidden + (size_t)tok * HH;
        for (int k = tid; k < HH; k += 256) {
            float hk = hrow[k];
            const float* c0 = cls_w + k * CC;
            const float* c1 = cls_w + (HH + k) * CC;
            const float* w0 = Wfc + k * CC;
            const float* w1 = Wfc + (HH + k) * CC;
#pragma unroll
            for (int c = 0; c < CC; ++c) {
                acc[0][c] += hk * c0[c];
                acc[1][c] += hk * c1[c];
                acc[2][c] += hk * w0[c];
                acc[3][c] += hk * w1[c];
            }
        }
#pragma unroll
        for (int g = 0; g < 4; ++g)
#pragma unroll
            for (int c = 0; c < CC; ++c)
#pragma unroll
                for (int off = 32; off > 0; off >>= 1) acc[g][c] += __shfl_down(acc[g][c], off, 64);
        __shared__ float sred2[4][4][CC];
        if (lane == 0)
#pragma unroll
            for (int g = 0; g < 4; ++g)
#pragma unroll
                for (int c = 0; c < CC; ++c) sred2[wave][g][c] = acc[g][c];
        __syncthreads();
        if (tid < 24) {
            int g = tid / CC, c = tid % CC;
            ws[TOK_OFF + g * TOKSZ + tok * CC + c] =
                sred2[0][g][c] + sred2[1][g][c] + sred2[2][g][c] + sred2[3][g][c];
        }
    }
}

// ---------------------------------------------------------------------------
// K3: 256 blocks (one per output row (b,i)) x 512 threads.
//  - s2[j] for all j of batch b (k-split 4-ways over the 8 waves)
//  - s1[i] for own i (block-wide reduction)
//  - shfl-scan plane math (validated in R3): pool0 -> alpha/beta -> pool1 -> Bf[j], Af[i]
//  - write out[b,i,:,:] (768 floats, float4-coalesced)
__global__ __launch_bounds__(512) void k3_plane_out(const float* __restrict__ hidden,
                                                    const float* __restrict__ mask_in,
                                                    const float* __restrict__ cls_b_g,
                                                    const float* __restrict__ ws,
                                                    float* __restrict__ out) {
    const int blk = blockIdx.x;
    const int b = blk >> 7, i = blk & 127;
    const int tid = threadIdx.x;
    const int wave = tid >> 6, lane = tid & 63;

    __shared__ float sm_sh[240];
    __shared__ float cb_sh[CC];
    __shared__ float s2q[4][LL][CC];   // four k-quarters of s2[j][c]
    __shared__ float s1red[8][CC];
    __shared__ float s1sh[CC];
    __shared__ float Bfsh[LL][CC];
    __shared__ float Afsh[CC];
    __shared__ float cfsh[CC];
    __shared__ float xw[2][CC + 1];

    if (tid < 240) sm_sh[tid] = ws[SM_OFF + tid];
    if (tid < CC) cb_sh[tid] = cls_b_g[tid];

    // ---- s2[j][c] = sum_{k<768} h[b][j][k] * WfWfc[768+k][c]  (quarter per wave-pair)
    {
        const float* Wf2b = ws + WFWFC_OFF + HH * CC;
        int j = tid & 127, quarter = tid >> 7;
        const float* hrow = hidden + ((size_t)(b * LL + j)) * HH + quarter * 192;
        const float* wbase = Wf2b + quarter * 192 * CC;
        float acc[CC] = {};
        for (int k = 0; k < 192; k += 4) {
            float4 hv = *(const float4*)(hrow + k);
            const float* w0 = wbase + k * CC;   // wave-uniform address
#pragma unroll
            for (int c = 0; c < CC; ++c) {
                acc[c] += hv.x * w0[c] + hv.y * w0[CC + c] + hv.z * w0[2 * CC + c] + hv.w * w0[3 * CC + c];
            }
        }
#pragma unroll
        for (int c = 0; c < CC; ++c) s2q[quarter][j][c] = acc[c];
    }
    // ---- s1[i][c] = sum_k h[b][i][k] * WfWfc[k][c]  (block reduction)
    {
        const float* Wf2t = ws + WFWFC_OFF;
        const float* hrow = hidden + ((size_t)(b * LL + i)) * HH;
        float acc[CC] = {};
        {
            float hk = hrow[tid];
            const float* w = Wf2t + tid * CC;
#pragma unroll
            for (int c = 0; c < CC; ++c) acc[c] += hk * w[c];
        }
        if (tid < 256) {
            float hk = hrow[512 + tid];
            const float* w = Wf2t + (512 + tid) * CC;
#pragma unroll
            for (int c = 0; c < CC; ++c) acc[c] += hk * w[c];
        }
#pragma unroll
        for (int c = 0; c < CC; ++c)
#pragma unroll
            for (int off = 32; off > 0; off >>= 1) acc[c] += __shfl_down(acc[c], off, 64);
        if (lane == 0)
#pragma unroll
            for (int c = 0; c < CC; ++c) s1red[wave][c] = acc[c];
    }
    __syncthreads();
    if (tid < CC) {
        float s = 0.f;
#pragma unroll
        for (int w = 0; w < 8; ++w) s += s1red[w][tid];
        s1sh[tid] = s;
    }
    __syncthreads();

    // ---- plane math on threads t = tid < 128 (validated shfl-scan, R3)
    const int t = tid;
    float p[CC], q[CC], al[CC], be[CC], pool0v[CC], pool1v[CC], gam[CC];
    float prefV[CC], sufV[CC], prefm = 1.f, sufm = 1.f, m_t = 0.f;
    bool mt = false;

    if (tid < LL) {
        m_t = mask_in[b * LL + t];
        mt = (m_t != 0.f);
#pragma unroll
        for (int c = 0; c < CC; ++c) {
            p[c] = ws[TOK_OFF + 0 * TOKSZ + (b * LL + t) * CC + c];
            q[c] = ws[TOK_OFF + 1 * TOKSZ + (b * LL + t) * CC + c];
        }
#pragma unroll
        for (int c = 0; c < CC; ++c) {
            float g = sm_sh[216 + c];
            for (int cp = 0; cp < CC; ++cp) g += cb_sh[cp] * sm_sh[cp * CC + c];
            gam[c] = g;
        }
#pragma unroll
        for (int c = 0; c < CC; ++c) {
            prefV[c] = mt ? p[c] : -INFINITY;
            sufV[c] = mt ? q[c] : -INFINITY;
        }
        prefm = m_t;
        sufm = m_t;
#pragma unroll
        for (int off = 1; off < 64; off <<= 1) {
#pragma unroll
            for (int c = 0; c < CC; ++c) {
                float v = __shfl_up(prefV[c], off, 64);
                if (lane >= off) prefV[c] = fmaxf(prefV[c], v);
                float u = __shfl_down(sufV[c], off, 64);
                if (lane < 64 - off) sufV[c] = fmaxf(sufV[c], u);
            }
            float vm = __shfl_up(prefm, off, 64);
            if (lane >= off) prefm = fminf(prefm, vm);
            float um = __shfl_down(sufm, off, 64);
            if (lane < 64 - off) sufm = fminf(sufm, um);
        }
        if (lane == 63 && wave == 0) {
#pragma unroll
            for (int c = 0; c < CC; ++c) xw[0][c] = prefV[c];
            xw[0][CC] = prefm;
        }
        if (lane == 0 && wave == 1) {
#pragma unroll
            for (int c = 0; c < CC; ++c) xw[1][c] = sufV[c];
            xw[1][CC] = sufm;
        }
    }
    __syncthreads();
    if (tid < LL) {
        if (wave == 1) {
#pragma unroll
            for (int c = 0; c < CC; ++c) prefV[c] = fmaxf(prefV[c], xw[0][c]);
            prefm = fminf(prefm, xw[0][CC]);
        } else {
#pragma unroll
            for (int c = 0; c < CC; ++c) sufV[c] = fmaxf(sufV[c], xw[1][c]);
            sufm = fminf(sufm, xw[1][CC]);
        }
        bool colz = (t < LL - 1) || (prefm == 0.f);
        bool rowz = (t > 0) || (sufm == 0.f);
#pragma unroll
        for (int c = 0; c < CC; ++c) {
            float cm = 0.f, rm = 0.f;
            if (mt) {
                cm = prefV[c] + q[c] + cb_sh[c];
                if (colz) cm = fmaxf(cm, 0.f);
                rm = p[c] + sufV[c] + cb_sh[c];
                if (rowz) rm = fmaxf(rm, 0.f);
            }
            pool0v[c] = fmaxf(cm, rm);
        }
#pragma unroll
        for (int c = 0; c < CC; ++c) {
            al[c] = ws[TOK_OFF + 2 * TOKSZ + (b * LL + t) * CC + c];
            be[c] = ws[TOK_OFF + 3 * TOKSZ + (b * LL + t) * CC + c];
        }
#pragma unroll
        for (int c = 0; c < CC; ++c)
            for (int cp = 0; cp < CC; ++cp) {
                al[c] += pool0v[cp] * sm_sh[36 + cp * CC + c] + p[cp] * sm_sh[cp * CC + c];
                be[c] += pool0v[cp] * sm_sh[72 + cp * CC + c] + q[cp] * sm_sh[cp * CC + c];
            }
#pragma unroll
        for (int c = 0; c < CC; ++c) {
            prefV[c] = mt ? al[c] : -INFINITY;
            sufV[c] = mt ? be[c] : -INFINITY;
        }
#pragma unroll
        for (int off = 1; off < 64; off <<= 1) {
#pragma unroll
            for (int c = 0; c < CC; ++c) {
                float v = __shfl_up(prefV[c], off, 64);
                if (lane >= off) prefV[c] = fmaxf(prefV[c], v);
                float u = __shfl_down(sufV[c], off, 64);
                if (lane < 64 - off) sufV[c] = fmaxf(sufV[c], u);
            }
        }
    }
    __syncthreads();   // xw reuse boundary
    if (tid < LL) {
        if (lane == 63 && wave == 0)
#pragma unroll
            for (int c = 0; c < CC; ++c) xw[0][c] = prefV[c];
        if (lane == 0 && wave == 1)
#pragma unroll
            for (int c = 0; c < CC; ++c) xw[1][c] = sufV[c];
    }
    __syncthreads();
    if (tid < LL) {
        if (wave == 1)
#pragma unroll
            for (int c = 0; c < CC; ++c) prefV[c] = fmaxf(prefV[c], xw[0][c]);
        else
#pragma unroll
            for (int c = 0; c < CC; ++c) sufV[c] = fmaxf(sufV[c], xw[1][c]);
        bool colz = (t < LL - 1) || (prefm == 0.f);
        bool rowz = (t > 0) || (sufm == 0.f);
#pragma unroll
        for (int c = 0; c < CC; ++c) {
            float cm = 0.f, rm = 0.f;
            if (mt) {
                cm = prefV[c] + be[c] + gam[c];
                if (colz) cm = fmaxf(cm, 0.f);
                rm = al[c] + sufV[c] + gam[c];
                if (rowz) rm = fmaxf(rm, 0.f);
            }
            pool1v[c] = fmaxf(cm, rm);
        }
        // Bf[t] (all t) and Af[i] (thread t == i)
#pragma unroll
        for (int c = 0; c < CC; ++c) {
            float Bv = s2q[0][t][c] + s2q[1][t][c] + s2q[2][t][c] + s2q[3][t][c];
            for (int cp = 0; cp < CC; ++cp) {
                Bv += pool0v[cp] * sm_sh[180 + cp * CC + c] + pool1v[cp] * sm_sh[72 + cp * CC + c]
                    + q[cp] * sm_sh[108 + cp * CC + c] + be[cp] * sm_sh[cp * CC + c];
            }
            Bfsh[t][c] = Bv;
        }
        if (t == i) {
#pragma unroll
            for (int c = 0; c < CC; ++c) {
                float A = s1sh[c];
                for (int cp = 0; cp < CC; ++cp) {
                    A += pool0v[cp] * sm_sh[144 + cp * CC + c] + pool1v[cp] * sm_sh[36 + cp * CC + c]
                       + p[cp] * sm_sh[108 + cp * CC + c] + al[cp] * sm_sh[cp * CC + c];
                }
                Afsh[c] = A;
            }
        }
        if (tid == 0) {
#pragma unroll
            for (int c = 0; c < CC; ++c) {
                float f = sm_sh[222 + c] + sm_sh[216 + c];
                for (int cp = 0; cp < CC; ++cp)
                    f += cb_sh[cp] * sm_sh[108 + cp * CC + c] + gam[cp] * sm_sh[cp * CC + c];
                cfsh[c] = f;
            }
        }
    }
    __syncthreads();
    // ---- write out[b,i,:,:]: 768 floats = 192 float4 lanes
    if (tid < (LL * CC) / 4) {
        int r = tid * 4;
        float4 o;
        float* op = &o.x;
#pragma unroll
        for (int k = 0; k < 4; ++k) {
            int idx = r + k;
            int c = idx % CC, j = idx / CC;
            op[k] = Afsh[c] + Bfsh[j][c] + cfsh[c];
        }
        *(float4*)(out + ((size_t)(b * LL + i)) * (LL * CC) + r) = o;
    }
}

// ---------------------------------------------------------------------------
extern "C" void kernel_launch(void* const* d_in, const int* in_sizes, int n_in,
                              void* d_out, int out_size, void* d_ws, size_t ws_size,
                              hipStream_t stream) {
    const float* hidden = (const float*)d_in[0];          // (2,128,768)
    const float* attention_mask = (const float*)d_in[1];  // (2,128)
    const float* cls_w = (const float*)d_in[2];           // (1536,6)
    const float* cls_b = (const float*)d_in[3];           // (6,)
    const float* feat_w = (const float*)d_in[4];          // (1554,1536)
    const float* feat_b = (const float*)d_in[5];          // (1536,)
    // d_in[6] = nhops, fixed at 2
    float* out = (float*)d_out;
    float* ws = (float*)d_ws;

    k1_wfc_dots<<<H2 + 114, 256, 0, stream>>>(feat_w, cls_w, cls_b, feat_b, ws);
    k2_wfwfc_dots_tok<<<H2 + 114 + NTOK, 256, 0, stream>>>(feat_w, cls_w, feat_b, hidden, ws);
    k3_plane_out<<<NTOK, 512, 0, stream>>>(hidden, attention_mask, cls_b, ws, out);
}

// Round 5
// 99.562 us; speedup vs baseline: 3.0333x; 1.2382x over previous
//
#include <hip/hip_runtime.h>
#include <math.h>

// Problem constants
#define BB 2
#define LL 128
#define HH 768
#define H2 1536          // 2*H
#define CC 6
#define NTOK (BB * LL)   // 256
#define TOKSZ (NTOK * CC)

// Workspace layout (float offsets)
#define WFC_OFF   0          // Wfc = Wf @ cls_w   (1536 x 6)
#define WFWFC_OFF 9216       // WfWfc = Wf @ Wfc   (1536 x 6)
#define SM_OFF    18432      // K1=0 M3=36 M4=72 K2=108 M3f=144 M4f=180 d1=216 dbfc=222
#define TOK_OFF   18672      // 6 arrays of TOKSZ: 0:p 1:q 2:r1 3:r2 4:s1 5:s2

// ---------------------------------------------------------------------------
// K1: blocks 0..1535   -> Wfc row k (feat_w row k @ cls_w)
//     blocks 1536..1649 -> 114 dot tasks vs cls_w (K1, M3, M4, d1)
// (validated R2/R4)
__global__ __launch_bounds__(256) void k1_wfc_dots(const float* __restrict__ feat_w,
                                                   const float* __restrict__ cls_w,
                                                   const float* __restrict__ cls_b,
                                                   const float* __restrict__ feat_b,
                                                   float* __restrict__ ws) {
    int blk = blockIdx.x, tid = threadIdx.x;
    int wave = tid >> 6, lane = tid & 63;
    if (blk < H2) {
        float acc[CC] = {};
        const float* arow = feat_w + (size_t)blk * H2;
        for (int r = tid; r < H2; r += 256) {
            float w = arow[r];
            const float* brow = cls_w + r * CC;
#pragma unroll
            for (int c = 0; c < CC; ++c) acc[c] += w * brow[c];
        }
#pragma unroll
        for (int c = 0; c < CC; ++c)
#pragma unroll
            for (int off = 32; off > 0; off >>= 1) acc[c] += __shfl_down(acc[c], off, 64);
        __shared__ float sred[4][CC];
        if (lane == 0)
#pragma unroll
            for (int c = 0; c < CC; ++c) sred[wave][c] = acc[c];
        __syncthreads();
        if (tid < CC)
            ws[WFC_OFF + blk * CC + tid] = sred[0][tid] + sred[1][tid] + sred[2][tid] + sred[3][tid];
    } else {
        int task = blk - H2;   // 0..113
        const float* va;
        int c, outIdx;
        bool add_clsb = false;
        if (task < 108) {
            int m = task / 36, e = task % 36, cp = e / CC;
            c = e % CC;
            int row = (m == 0) ? (H2 + 2 * CC) : ((m == 1) ? H2 : (H2 + CC)); // K1:W5 M3:W3 M4:W4
            va = feat_w + (size_t)(row + cp) * H2;
            outIdx = m * 36 + e;
        } else {
            c = task - 108;
            va = feat_b;
            outIdx = 216 + c;
            add_clsb = true;
        }
        float acc = 0.f;
        for (int r = tid; r < H2; r += 256) acc += va[r] * cls_w[r * CC + c];
#pragma unroll
        for (int off = 32; off > 0; off >>= 1) acc += __shfl_down(acc, off, 64);
        __shared__ float sred1[4];
        if (lane == 0) sred1[wave] = acc;
        __syncthreads();
        if (tid == 0) {
            float v = sred1[0] + sred1[1] + sred1[2] + sred1[3];
            if (add_clsb) v += cls_b[c];
            ws[SM_OFF + outIdx] = v;
        }
    }
}

// ---------------------------------------------------------------------------
// K2: blocks 0..1535    -> WfWfc row k (feat_w row k @ Wfc)
//     blocks 1536..1649 -> 114 dot tasks vs Wfc (K2, M3f, M4f, dbfc)
//     blocks 1650..1905 -> token projections p,q,r1,r2 for token (blk-1650)
// (validated R2/R4)
__global__ __launch_bounds__(256) void k2_wfwfc_dots_tok(const float* __restrict__ feat_w,
                                                         const float* __restrict__ cls_w,
                                                         const float* __restrict__ feat_b,
                                                         const float* __restrict__ hidden,
                                                         float* __restrict__ ws) {
    const float* Wfc = ws + WFC_OFF;
    int blk = blockIdx.x, tid = threadIdx.x;
    int wave = tid >> 6, lane = tid & 63;
    if (blk < H2) {
        float acc[CC] = {};
        const float* arow = feat_w + (size_t)blk * H2;
        for (int r = tid; r < H2; r += 256) {
            float w = arow[r];
            const float* brow = Wfc + r * CC;
#pragma unroll
            for (int c = 0; c < CC; ++c) acc[c] += w * brow[c];
        }
#pragma unroll
        for (int c = 0; c < CC; ++c)
#pragma unroll
            for (int off = 32; off > 0; off >>= 1) acc[c] += __shfl_down(acc[c], off, 64);
        __shared__ float sred[4][CC];
        if (lane == 0)
#pragma unroll
            for (int c = 0; c < CC; ++c) sred[wave][c] = acc[c];
        __syncthreads();
        if (tid < CC)
            ws[WFWFC_OFF + blk * CC + tid] = sred[0][tid] + sred[1][tid] + sred[2][tid] + sred[3][tid];
    } else if (blk < H2 + 114) {
        int task = blk - H2;
        const float* va;
        int c, outIdx;
        if (task < 108) {
            int m = task / 36, e = task % 36, cp = e / CC;
            c = e % CC;
            int row = (m == 0) ? (H2 + 2 * CC) : ((m == 1) ? H2 : (H2 + CC)); // K2 M3f M4f
            va = feat_w + (size_t)(row + cp) * H2;
            outIdx = (m + 3) * 36 + e;  // 108 / 144 / 180
        } else {
            c = task - 108;
            va = feat_b;
            outIdx = 222 + c;
        }
        float acc = 0.f;
        for (int r = tid; r < H2; r += 256) acc += va[r] * Wfc[r * CC + c];
#pragma unroll
        for (int off = 32; off > 0; off >>= 1) acc += __shfl_down(acc, off, 64);
        __shared__ float sred1[4];
        if (lane == 0) sred1[wave] = acc;
        __syncthreads();
        if (tid == 0) ws[SM_OFF + outIdx] = sred1[0] + sred1[1] + sred1[2] + sred1[3];
    } else {
        int tok = blk - (H2 + 114);
        float acc[4][CC] = {};
        const float* hrow = hidden + (size_t)tok * HH;
        for (int k = tid; k < HH; k += 256) {
            float hk = hrow[k];
            const float* c0 = cls_w + k * CC;
            const float* c1 = cls_w + (HH + k) * CC;
            const float* w0 = Wfc + k * CC;
            const float* w1 = Wfc + (HH + k) * CC;
#pragma unroll
            for (int c = 0; c < CC; ++c) {
                acc[0][c] += hk * c0[c];
                acc[1][c] += hk * c1[c];
                acc[2][c] += hk * w0[c];
                acc[3][c] += hk * w1[c];
            }
        }
#pragma unroll
        for (int g = 0; g < 4; ++g)
#pragma unroll
            for (int c = 0; c < CC; ++c)
#pragma unroll
                for (int off = 32; off > 0; off >>= 1) acc[g][c] += __shfl_down(acc[g][c], off, 64);
        __shared__ float sred2[4][4][CC];
        if (lane == 0)
#pragma unroll
            for (int g = 0; g < 4; ++g)
#pragma unroll
                for (int c = 0; c < CC; ++c) sred2[wave][g][c] = acc[g][c];
        __syncthreads();
        if (tid < 24) {
            int g = tid / CC, c = tid % CC;
            ws[TOK_OFF + g * TOKSZ + tok * CC + c] =
                sred2[0][g][c] + sred2[1][g][c] + sred2[2][g][c] + sred2[3][g][c];
        }
    }
}

// ---------------------------------------------------------------------------
// K3: 256 blocks -> token projections s1,s2 vs WfWfc (validated R2)
__global__ __launch_bounds__(256) void k3_tok_s(const float* __restrict__ hidden,
                                                float* __restrict__ ws) {
    const float* Wf2 = ws + WFWFC_OFF;
    int tok = blockIdx.x, tid = threadIdx.x;
    int wave = tid >> 6, lane = tid & 63;
    float acc[2][CC] = {};
    const float* hrow = hidden + (size_t)tok * HH;
    for (int k = tid; k < HH; k += 256) {
        float hk = hrow[k];
        const float* v0 = Wf2 + k * CC;
        const float* v1 = Wf2 + (HH + k) * CC;
#pragma unroll
        for (int c = 0; c < CC; ++c) {
            acc[0][c] += hk * v0[c];
            acc[1][c] += hk * v1[c];
        }
    }
#pragma unroll
    for (int g = 0; g < 2; ++g)
#pragma unroll
        for (int c = 0; c < CC; ++c)
#pragma unroll
            for (int off = 32; off > 0; off >>= 1) acc[g][c] += __shfl_down(acc[g][c], off, 64);
    __shared__ float sred[4][2][CC];
    if (lane == 0)
#pragma unroll
        for (int g = 0; g < 2; ++g)
#pragma unroll
            for (int c = 0; c < CC; ++c) sred[wave][g][c] = acc[g][c];
    __syncthreads();
    if (tid < 12) {
        int g = tid / CC, c = tid % CC;
        ws[TOK_OFF + (4 + g) * TOKSZ + tok * CC + c] =
            sred[0][g][c] + sred[1][g][c] + sred[2][g][c] + sred[3][g][c];
    }
}

// ---------------------------------------------------------------------------
// K4: 256 blocks (one per output row (b,i)) x 256 threads.
// Shfl-scan plane math (validated R3/R4) with s1/s2 LOADED from ws,
// then write out[b,i,:,:] (768 floats, float4-coalesced).
__global__ __launch_bounds__(256) void k4_plane_out(const float* __restrict__ mask_in,
                                                    const float* __restrict__ cls_b_g,
                                                    const float* __restrict__ ws,
                                                    float* __restrict__ out) {
    const int blk = blockIdx.x;
    const int b = blk >> 7, i = blk & 127;
    const int tid = threadIdx.x;
    const int wave = tid >> 6, lane = tid & 63;

    __shared__ float sm_sh[240];
    __shared__ float cb_sh[CC];
    __shared__ float Bfsh[LL][CC];
    __shared__ float Afsh[CC];
    __shared__ float cfsh[CC];
    __shared__ float xw[2][CC + 1];

    if (tid < 240) sm_sh[tid] = ws[SM_OFF + tid];
    if (tid < CC) cb_sh[tid] = cls_b_g[tid];
    __syncthreads();

    // ---- plane math on threads t = tid < 128 (validated shfl-scan)
    const int t = tid;
    float p[CC], q[CC], al[CC], be[CC], pool0v[CC], pool1v[CC], gam[CC];
    float prefV[CC], sufV[CC], prefm = 1.f, sufm = 1.f, m_t = 0.f;
    bool mt = false;

    if (tid < LL) {
        m_t = mask_in[b * LL + t];
        mt = (m_t != 0.f);
#pragma unroll
        for (int c = 0; c < CC; ++c) {
            p[c] = ws[TOK_OFF + 0 * TOKSZ + (b * LL + t) * CC + c];
            q[c] = ws[TOK_OFF + 1 * TOKSZ + (b * LL + t) * CC + c];
        }
#pragma unroll
        for (int c = 0; c < CC; ++c) {
            float g = sm_sh[216 + c];
            for (int cp = 0; cp < CC; ++cp) g += cb_sh[cp] * sm_sh[cp * CC + c];
            gam[c] = g;
        }
#pragma unroll
        for (int c = 0; c < CC; ++c) {
            prefV[c] = mt ? p[c] : -INFINITY;
            sufV[c] = mt ? q[c] : -INFINITY;
        }
        prefm = m_t;
        sufm = m_t;
#pragma unroll
        for (int off = 1; off < 64; off <<= 1) {
#pragma unroll
            for (int c = 0; c < CC; ++c) {
                float v = __shfl_up(prefV[c], off, 64);
                if (lane >= off) prefV[c] = fmaxf(prefV[c], v);
                float u = __shfl_down(sufV[c], off, 64);
                if (lane < 64 - off) sufV[c] = fmaxf(sufV[c], u);
            }
            float vm = __shfl_up(prefm, off, 64);
            if (lane >= off) prefm = fminf(prefm, vm);
            float um = __shfl_down(sufm, off, 64);
            if (lane < 64 - off) sufm = fminf(sufm, um);
        }
        if (lane == 63 && wave == 0) {
#pragma unroll
            for (int c = 0; c < CC; ++c) xw[0][c] = prefV[c];
            xw[0][CC] = prefm;
        }
        if (lane == 0 && wave == 1) {
#pragma unroll
            for (int c = 0; c < CC; ++c) xw[1][c] = sufV[c];
            xw[1][CC] = sufm;
        }
    }
    __syncthreads();
    if (tid < LL) {
        if (wave == 1) {
#pragma unroll
            for (int c = 0; c < CC; ++c) prefV[c] = fmaxf(prefV[c], xw[0][c]);
            prefm = fminf(prefm, xw[0][CC]);
        } else {
#pragma unroll
            for (int c = 0; c < CC; ++c) sufV[c] = fmaxf(sufV[c], xw[1][c]);
            sufm = fminf(sufm, xw[1][CC]);
        }
        bool colz = (t < LL - 1) || (prefm == 0.f);
        bool rowz = (t > 0) || (sufm == 0.f);
#pragma unroll
        for (int c = 0; c < CC; ++c) {
            float cm = 0.f, rm = 0.f;
            if (mt) {
                cm = prefV[c] + q[c] + cb_sh[c];
                if (colz) cm = fmaxf(cm, 0.f);
                rm = p[c] + sufV[c] + cb_sh[c];
                if (rowz) rm = fmaxf(rm, 0.f);
            }
            pool0v[c] = fmaxf(cm, rm);
        }
#pragma unroll
        for (int c = 0; c < CC; ++c) {
            al[c] = ws[TOK_OFF + 2 * TOKSZ + (b * LL + t) * CC + c];
            be[c] = ws[TOK_OFF + 3 * TOKSZ + (b * LL + t) * CC + c];
        }
#pragma unroll
        for (int c = 0; c < CC; ++c)
            for (int cp = 0; cp < CC; ++cp) {
                al[c] += pool0v[cp] * sm_sh[36 + cp * CC + c] + p[cp] * sm_sh[cp * CC + c];
                be[c] += pool0v[cp] * sm_sh[72 + cp * CC + c] + q[cp] * sm_sh[cp * CC + c];
            }
#pragma unroll
        for (int c = 0; c < CC; ++c) {
            prefV[c] = mt ? al[c] : -INFINITY;
            sufV[c] = mt ? be[c] : -INFINITY;
        }
#pragma unroll
        for (int off = 1; off < 64; off <<= 1) {
#pragma unroll
            for (int c = 0; c < CC; ++c) {
                float v = __shfl_up(prefV[c], off, 64);
                if (lane >= off) prefV[c] = fmaxf(prefV[c], v);
                float u = __shfl_down(sufV[c], off, 64);
                if (lane < 64 - off) sufV[c] = fmaxf(sufV[c], u);
            }
        }
    }
    __syncthreads();   // xw reuse boundary
    if (tid < LL) {
        if (lane == 63 && wave == 0)
#pragma unroll
            for (int c = 0; c < CC; ++c) xw[0][c] = prefV[c];
        if (lane == 0 && wave == 1)
#pragma unroll
            for (int c = 0; c < CC; ++c) xw[1][c] = sufV[c];
    }
    __syncthreads();
    if (tid < LL) {
        if (wave == 1)
#pragma unroll
            for (int c = 0; c < CC; ++c) prefV[c] = fmaxf(prefV[c], xw[0][c]);
        else
#pragma unroll
            for (int c = 0; c < CC; ++c) sufV[c] = fmaxf(sufV[c], xw[1][c]);
        bool colz = (t < LL - 1) || (prefm == 0.f);
        bool rowz = (t > 0) || (sufm == 0.f);
#pragma unroll
        for (int c = 0; c < CC; ++c) {
            float cm = 0.f, rm = 0.f;
            if (mt) {
                cm = prefV[c] + be[c] + gam[c];
                if (colz) cm = fmaxf(cm, 0.f);
                rm = al[c] + sufV[c] + gam[c];
                if (rowz) rm = fmaxf(rm, 0.f);
            }
            pool1v[c] = fmaxf(cm, rm);
        }
        // Bf[t] (all t) from loaded s2; Af[i] (thread t == i) from loaded s1
#pragma unroll
        for (int c = 0; c < CC; ++c) {
            float Bv = ws[TOK_OFF + 5 * TOKSZ + (b * LL + t) * CC + c];
            for (int cp = 0; cp < CC; ++cp) {
                Bv += pool0v[cp] * sm_sh[180 + cp * CC + c] + pool1v[cp] * sm_sh[72 + cp * CC + c]
                    + q[cp] * sm_sh[108 + cp * CC + c] + be[cp] * sm_sh[cp * CC + c];
            }
            Bfsh[t][c] = Bv;
        }
        if (t == i) {
#pragma unroll
            for (int c = 0; c < CC; ++c) {
                float A = ws[TOK_OFF + 4 * TOKSZ + (b * LL + i) * CC + c];
                for (int cp = 0; cp < CC; ++cp) {
                    A += pool0v[cp] * sm_sh[144 + cp * CC + c] + pool1v[cp] * sm_sh[36 + cp * CC + c]
                       + p[cp] * sm_sh[108 + cp * CC + c] + al[cp] * sm_sh[cp * CC + c];
                }
                Afsh[c] = A;
            }
        }
        if (tid == 0) {
#pragma unroll
            for (int c = 0; c < CC; ++c) {
                float f = sm_sh[222 + c] + sm_sh[216 + c];
                for (int cp = 0; cp < CC; ++cp)
                    f += cb_sh[cp] * sm_sh[108 + cp * CC + c] + gam[cp] * sm_sh[cp * CC + c];
                cfsh[c] = f;
            }
        }
    }
    __syncthreads();
    // ---- write out[b,i,:,:]: 768 floats = 192 float4 lanes
    if (tid < (LL * CC) / 4) {
        int r = tid * 4;
        float4 o;
        float* op = &o.x;
#pragma unroll
        for (int k = 0; k < 4; ++k) {
            int idx = r + k;
            int c = idx % CC, j = idx / CC;
            op[k] = Afsh[c] + Bfsh[j][c] + cfsh[c];
        }
        *(float4*)(out + ((size_t)(b * LL + i)) * (LL * CC) + r) = o;
    }
}

// ---------------------------------------------------------------------------
extern "C" void kernel_launch(void* const* d_in, const int* in_sizes, int n_in,
                              void* d_out, int out_size, void* d_ws, size_t ws_size,
                              hipStream_t stream) {
    const float* hidden = (const float*)d_in[0];          // (2,128,768)
    const float* attention_mask = (const float*)d_in[1];  // (2,128)
    const float* cls_w = (const float*)d_in[2];           // (1536,6)
    const float* cls_b = (const float*)d_in[3];           // (6,)
    const float* feat_w = (const float*)d_in[4];          // (1554,1536)
    const float* feat_b = (const float*)d_in[5];          // (1536,)
    // d_in[6] = nhops, fixed at 2
    float* out = (float*)d_out;
    float* ws = (float*)d_ws;

    k1_wfc_dots<<<H2 + 114, 256, 0, stream>>>(feat_w, cls_w, cls_b, feat_b, ws);
    k2_wfwfc_dots_tok<<<H2 + 114 + NTOK, 256, 0, stream>>>(feat_w, cls_w, feat_b, hidden, ws);
    k3_tok_s<<<NTOK, 256, 0, stream>>>(hidden, ws);
    k4_plane_out<<<NTOK, 256, 0, stream>>>(attention_mask, cls_b, ws, out);
}

// Round 6
// 99.534 us; speedup vs baseline: 3.0342x; 1.0003x over previous
//
#include <hip/hip_runtime.h>
#include <math.h>

// Problem constants
#define BB 2
#define LL 128
#define HH 768
#define H2 1536          // 2*H
#define CC 6
#define NTOK (BB * LL)   // 256
#define TOKSZ (NTOK * CC)

// Workspace layout (float offsets)
#define WFC_OFF   0          // Wfc = Wf @ cls_w   (1536 x 6)
#define WFWFC_OFF 9216       // WfWfc = Wf @ Wfc   (1536 x 6)
#define SM_OFF    18432      // K1=0 M3=36 M4=72 K2=108 M3f=144 M4f=180 d1=216 dbfc=222
#define TOK_OFF   18672      // 6 arrays of TOKSZ: 0:p 1:q 2:r1 3:r2 4:s1 5:s2

// ---------------------------------------------------------------------------
// Vectorized row-dot: thread tid handles elements r in [6*tid, 6*tid+6).
// arow: 3x float2 (8B-aligned). Bmat slab [r*6, r*6+36): 9x float4 (16B-aligned).
__device__ __forceinline__ void rowdot6(const float* __restrict__ arow,
                                        const float* __restrict__ Bmat,
                                        int tid, float acc[CC]) {
    const int r0 = tid * CC;
    const float2* A2 = (const float2*)(arow + r0);
    float2 A01 = A2[0], A23 = A2[1], A45 = A2[2];
    float a[6] = {A01.x, A01.y, A23.x, A23.y, A45.x, A45.y};
    const float4* B4 = (const float4*)(Bmat + (size_t)r0 * CC);
    float w[36];
#pragma unroll
    for (int t4 = 0; t4 < 9; ++t4) {
        float4 v = B4[t4];
        w[4 * t4 + 0] = v.x; w[4 * t4 + 1] = v.y; w[4 * t4 + 2] = v.z; w[4 * t4 + 3] = v.w;
    }
#pragma unroll
    for (int u = 0; u < 6; ++u)
#pragma unroll
        for (int c = 0; c < CC; ++c) acc[c] += a[u] * w[u * CC + c];
}

// ---------------------------------------------------------------------------
// K1: blocks 0..1535   -> Wfc row k (feat_w row k @ cls_w)   [vectorized]
//     blocks 1536..1649 -> 114 dot tasks vs cls_w (K1, M3, M4, d1)
__global__ __launch_bounds__(256) void k1_wfc_dots(const float* __restrict__ feat_w,
                                                   const float* __restrict__ cls_w,
                                                   const float* __restrict__ cls_b,
                                                   const float* __restrict__ feat_b,
                                                   float* __restrict__ ws) {
    int blk = blockIdx.x, tid = threadIdx.x;
    int wave = tid >> 6, lane = tid & 63;
    if (blk < H2) {
        float acc[CC] = {};
        rowdot6(feat_w + (size_t)blk * H2, cls_w, tid, acc);
#pragma unroll
        for (int c = 0; c < CC; ++c)
#pragma unroll
            for (int off = 32; off > 0; off >>= 1) acc[c] += __shfl_down(acc[c], off, 64);
        __shared__ float sred[4][CC];
        if (lane == 0)
#pragma unroll
            for (int c = 0; c < CC; ++c) sred[wave][c] = acc[c];
        __syncthreads();
        if (tid < CC)
            ws[WFC_OFF + blk * CC + tid] = sred[0][tid] + sred[1][tid] + sred[2][tid] + sred[3][tid];
    } else {
        int task = blk - H2;   // 0..113
        const float* va;
        int c, outIdx;
        bool add_clsb = false;
        if (task < 108) {
            int m = task / 36, e = task % 36, cp = e / CC;
            c = e % CC;
            int row = (m == 0) ? (H2 + 2 * CC) : ((m == 1) ? H2 : (H2 + CC)); // K1:W5 M3:W3 M4:W4
            va = feat_w + (size_t)(row + cp) * H2;
            outIdx = m * 36 + e;
        } else {
            c = task - 108;
            va = feat_b;
            outIdx = 216 + c;
            add_clsb = true;
        }
        float acc = 0.f;
        for (int r = tid; r < H2; r += 256) acc += va[r] * cls_w[r * CC + c];
#pragma unroll
        for (int off = 32; off > 0; off >>= 1) acc += __shfl_down(acc, off, 64);
        __shared__ float sred1[4];
        if (lane == 0) sred1[wave] = acc;
        __syncthreads();
        if (tid == 0) {
            float v = sred1[0] + sred1[1] + sred1[2] + sred1[3];
            if (add_clsb) v += cls_b[c];
            ws[SM_OFF + outIdx] = v;
        }
    }
}

// ---------------------------------------------------------------------------
// K2: blocks 0..1535    -> WfWfc row k (feat_w row k @ Wfc)   [vectorized]
//     blocks 1536..1649 -> 114 dot tasks vs Wfc (K2, M3f, M4f, dbfc)
//     blocks 1650..1905 -> token projections p,q,r1,r2 for token (blk-1650)
__global__ __launch_bounds__(256) void k2_wfwfc_dots_tok(const float* __restrict__ feat_w,
                                                         const float* __restrict__ cls_w,
                                                         const float* __restrict__ feat_b,
                                                         const float* __restrict__ hidden,
                                                         float* __restrict__ ws) {
    const float* Wfc = ws + WFC_OFF;
    int blk = blockIdx.x, tid = threadIdx.x;
    int wave = tid >> 6, lane = tid & 63;
    if (blk < H2) {
        float acc[CC] = {};
        rowdot6(feat_w + (size_t)blk * H2, Wfc, tid, acc);
#pragma unroll
        for (int c = 0; c < CC; ++c)
#pragma unroll
            for (int off = 32; off > 0; off >>= 1) acc[c] += __shfl_down(acc[c], off, 64);
        __shared__ float sred[4][CC];
        if (lane == 0)
#pragma unroll
            for (int c = 0; c < CC; ++c) sred[wave][c] = acc[c];
        __syncthreads();
        if (tid < CC)
            ws[WFWFC_OFF + blk * CC + tid] = sred[0][tid] + sred[1][tid] + sred[2][tid] + sred[3][tid];
    } else if (blk < H2 + 114) {
        int task = blk - H2;
        const float* va;
        int c, outIdx;
        if (task < 108) {
            int m = task / 36, e = task % 36, cp = e / CC;
            c = e % CC;
            int row = (m == 0) ? (H2 + 2 * CC) : ((m == 1) ? H2 : (H2 + CC)); // K2 M3f M4f
            va = feat_w + (size_t)(row + cp) * H2;
            outIdx = (m + 3) * 36 + e;  // 108 / 144 / 180
        } else {
            c = task - 108;
            va = feat_b;
            outIdx = 222 + c;
        }
        float acc = 0.f;
        for (int r = tid; r < H2; r += 256) acc += va[r] * Wfc[r * CC + c];
#pragma unroll
        for (int off = 32; off > 0; off >>= 1) acc += __shfl_down(acc, off, 64);
        __shared__ float sred1[4];
        if (lane == 0) sred1[wave] = acc;
        __syncthreads();
        if (tid == 0) ws[SM_OFF + outIdx] = sred1[0] + sred1[1] + sred1[2] + sred1[3];
    } else {
        int tok = blk - (H2 + 114);
        float acc[4][CC] = {};
        const float* hrow = hidden + (size_t)tok * HH;
        for (int k = tid; k < HH; k += 256) {
            float hk = hrow[k];
            const float* c0 = cls_w + k * CC;
            const float* c1 = cls_w + (HH + k) * CC;
            const float* w0 = Wfc + k * CC;
            const float* w1 = Wfc + (HH + k) * CC;
#pragma unroll
            for (int c = 0; c < CC; ++c) {
                acc[0][c] += hk * c0[c];
                acc[1][c] += hk * c1[c];
                acc[2][c] += hk * w0[c];
                acc[3][c] += hk * w1[c];
            }
        }
#pragma unroll
        for (int g = 0; g < 4; ++g)
#pragma unroll
            for (int c = 0; c < CC; ++c)
#pragma unroll
                for (int off = 32; off > 0; off >>= 1) acc[g][c] += __shfl_down(acc[g][c], off, 64);
        __shared__ float sred2[4][4][CC];
        if (lane == 0)
#pragma unroll
            for (int g = 0; g < 4; ++g)
#pragma unroll
                for (int c = 0; c < CC; ++c) sred2[wave][g][c] = acc[g][c];
        __syncthreads();
        if (tid < 24) {
            int g = tid / CC, c = tid % CC;
            ws[TOK_OFF + g * TOKSZ + tok * CC + c] =
                sred2[0][g][c] + sred2[1][g][c] + sred2[2][g][c] + sred2[3][g][c];
        }
    }
}

// ---------------------------------------------------------------------------
// K3: 256 blocks -> token projections s1,s2 vs WfWfc (validated R2/R5)
__global__ __launch_bounds__(256) void k3_tok_s(const float* __restrict__ hidden,
                                                float* __restrict__ ws) {
    const float* Wf2 = ws + WFWFC_OFF;
    int tok = blockIdx.x, tid = threadIdx.x;
    int wave = tid >> 6, lane = tid & 63;
    float acc[2][CC] = {};
    const float* hrow = hidden + (size_t)tok * HH;
    for (int k = tid; k < HH; k += 256) {
        float hk = hrow[k];
        const float* v0 = Wf2 + k * CC;
        const float* v1 = Wf2 + (HH + k) * CC;
#pragma unroll
        for (int c = 0; c < CC; ++c) {
            acc[0][c] += hk * v0[c];
            acc[1][c] += hk * v1[c];
        }
    }
#pragma unroll
    for (int g = 0; g < 2; ++g)
#pragma unroll
        for (int c = 0; c < CC; ++c)
#pragma unroll
            for (int off = 32; off > 0; off >>= 1) acc[g][c] += __shfl_down(acc[g][c], off, 64);
    __shared__ float sred[4][2][CC];
    if (lane == 0)
#pragma unroll
        for (int g = 0; g < 2; ++g)
#pragma unroll
            for (int c = 0; c < CC; ++c) sred[wave][g][c] = acc[g][c];
    __syncthreads();
    if (tid < 12) {
        int g = tid / CC, c = tid % CC;
        ws[TOK_OFF + (4 + g) * TOKSZ + tok * CC + c] =
            sred[0][g][c] + sred[1][g][c] + sred[2][g][c] + sred[3][g][c];
    }
}

// ---------------------------------------------------------------------------
// K4: 256 blocks (one per output row (b,i)) x 256 threads.
// Shfl-scan plane math (validated R3/R4/R5) with s1/s2 loaded from ws,
// then write out[b,i,:,:] (768 floats, float4-coalesced).
__global__ __launch_bounds__(256) void k4_plane_out(const float* __restrict__ mask_in,
                                                    const float* __restrict__ cls_b_g,
                                                    const float* __restrict__ ws,
                                                    float* __restrict__ out) {
    const int blk = blockIdx.x;
    const int b = blk >> 7, i = blk & 127;
    const int tid = threadIdx.x;
    const int wave = tid >> 6, lane = tid & 63;

    __shared__ float sm_sh[240];
    __shared__ float cb_sh[CC];
    __shared__ float Bfsh[LL][CC];
    __shared__ float Afsh[CC];
    __shared__ float cfsh[CC];
    __shared__ float xw[2][CC + 1];

    if (tid < 240) sm_sh[tid] = ws[SM_OFF + tid];
    if (tid < CC) cb_sh[tid] = cls_b_g[tid];
    __syncthreads();

    const int t = tid;
    float p[CC], q[CC], al[CC], be[CC], pool0v[CC], pool1v[CC], gam[CC];
    float prefV[CC], sufV[CC], prefm = 1.f, sufm = 1.f, m_t = 0.f;
    bool mt = false;

    if (tid < LL) {
        m_t = mask_in[b * LL + t];
        mt = (m_t != 0.f);
#pragma unroll
        for (int c = 0; c < CC; ++c) {
            p[c] = ws[TOK_OFF + 0 * TOKSZ + (b * LL + t) * CC + c];
            q[c] = ws[TOK_OFF + 1 * TOKSZ + (b * LL + t) * CC + c];
        }
#pragma unroll
        for (int c = 0; c < CC; ++c) {
            float g = sm_sh[216 + c];
            for (int cp = 0; cp < CC; ++cp) g += cb_sh[cp] * sm_sh[cp * CC + c];
            gam[c] = g;
        }
#pragma unroll
        for (int c = 0; c < CC; ++c) {
            prefV[c] = mt ? p[c] : -INFINITY;
            sufV[c] = mt ? q[c] : -INFINITY;
        }
        prefm = m_t;
        sufm = m_t;
#pragma unroll
        for (int off = 1; off < 64; off <<= 1) {
#pragma unroll
            for (int c = 0; c < CC; ++c) {
                float v = __shfl_up(prefV[c], off, 64);
                if (lane >= off) prefV[c] = fmaxf(prefV[c], v);
                float u = __shfl_down(sufV[c], off, 64);
                if (lane < 64 - off) sufV[c] = fmaxf(sufV[c], u);
            }
            float vm = __shfl_up(prefm, off, 64);
            if (lane >= off) prefm = fminf(prefm, vm);
            float um = __shfl_down(sufm, off, 64);
            if (lane < 64 - off) sufm = fminf(sufm, um);
        }
        if (lane == 63 && wave == 0) {
#pragma unroll
            for (int c = 0; c < CC; ++c) xw[0][c] = prefV[c];
            xw[0][CC] = prefm;
        }
        if (lane == 0 && wave == 1) {
#pragma unroll
            for (int c = 0; c < CC; ++c) xw[1][c] = sufV[c];
            xw[1][CC] = sufm;
        }
    }
    __syncthreads();
    if (tid < LL) {
        if (wave == 1) {
#pragma unroll
            for (int c = 0; c < CC; ++c) prefV[c] = fmaxf(prefV[c], xw[0][c]);
            prefm = fminf(prefm, xw[0][CC]);
        } else {
#pragma unroll
            for (int c = 0; c < CC; ++c) sufV[c] = fmaxf(sufV[c], xw[1][c]);
            sufm = fminf(sufm, xw[1][CC]);
        }
        bool colz = (t < LL - 1) || (prefm == 0.f);
        bool rowz = (t > 0) || (sufm == 0.f);
#pragma unroll
        for (int c = 0; c < CC; ++c) {
            float cm = 0.f, rm = 0.f;
            if (mt) {
                cm = prefV[c] + q[c] + cb_sh[c];
                if (colz) cm = fmaxf(cm, 0.f);
                rm = p[c] + sufV[c] + cb_sh[c];
                if (rowz) rm = fmaxf(rm, 0.f);
            }
            pool0v[c] = fmaxf(cm, rm);
        }
#pragma unroll
        for (int c = 0; c < CC; ++c) {
            al[c] = ws[TOK_OFF + 2 * TOKSZ + (b * LL + t) * CC + c];
            be[c] = ws[TOK_OFF + 3 * TOKSZ + (b * LL + t) * CC + c];
        }
#pragma unroll
        for (int c = 0; c < CC; ++c)
            for (int cp = 0; cp < CC; ++cp) {
                al[c] += pool0v[cp] * sm_sh[36 + cp * CC + c] + p[cp] * sm_sh[cp * CC + c];
                be[c] += pool0v[cp] * sm_sh[72 + cp * CC + c] + q[cp] * sm_sh[cp * CC + c];
            }
#pragma unroll
        for (int c = 0; c < CC; ++c) {
            prefV[c] = mt ? al[c] : -INFINITY;
            sufV[c] = mt ? be[c] : -INFINITY;
        }
#pragma unroll
        for (int off = 1; off < 64; off <<= 1) {
#pragma unroll
            for (int c = 0; c < CC; ++c) {
                float v = __shfl_up(prefV[c], off, 64);
                if (lane >= off) prefV[c] = fmaxf(prefV[c], v);
                float u = __shfl_down(sufV[c], off, 64);
                if (lane < 64 - off) sufV[c] = fmaxf(sufV[c], u);
            }
        }
    }
    __syncthreads();   // xw reuse boundary
    if (tid < LL) {
        if (lane == 63 && wave == 0)
#pragma unroll
            for (int c = 0; c < CC; ++c) xw[0][c] = prefV[c];
        if (lane == 0 && wave == 1)
#pragma unroll
            for (int c = 0; c < CC; ++c) xw[1][c] = sufV[c];
    }
    __syncthreads();
    if (tid < LL) {
        if (wave == 1)
#pragma unroll
            for (int c = 0; c < CC; ++c) prefV[c] = fmaxf(prefV[c], xw[0][c]);
        else
#pragma unroll
            for (int c = 0; c < CC; ++c) sufV[c] = fmaxf(sufV[c], xw[1][c]);
        bool colz = (t < LL - 1) || (prefm == 0.f);
        bool rowz = (t > 0) || (sufm == 0.f);
#pragma unroll
        for (int c = 0; c < CC; ++c) {
            float cm = 0.f, rm = 0.f;
            if (mt) {
                cm = prefV[c] + be[c] + gam[c];
                if (colz) cm = fmaxf(cm, 0.f);
                rm = al[c] + sufV[c] + gam[c];
                if (rowz) rm = fmaxf(rm, 0.f);
            }
            pool1v[c] = fmaxf(cm, rm);
        }
        // Bf[t] (all t) from loaded s2; Af[i] (thread t == i) from loaded s1
#pragma unroll
        for (int c = 0; c < CC; ++c) {
            float Bv = ws[TOK_OFF + 5 * TOKSZ + (b * LL + t) * CC + c];
            for (int cp = 0; cp < CC; ++cp) {
                Bv += pool0v[cp] * sm_sh[180 + cp * CC + c] + pool1v[cp] * sm_sh[72 + cp * CC + c]
                    + q[cp] * sm_sh[108 + cp * CC + c] + be[cp] * sm_sh[cp * CC + c];
            }
            Bfsh[t][c] = Bv;
        }
        if (t == i) {
#pragma unroll
            for (int c = 0; c < CC; ++c) {
                float A = ws[TOK_OFF + 4 * TOKSZ + (b * LL + i) * CC + c];
                for (int cp = 0; cp < CC; ++cp) {
                    A += pool0v[cp] * sm_sh[144 + cp * CC + c] + pool1v[cp] * sm_sh[36 + cp * CC + c]
                       + p[cp] * sm_sh[108 + cp * CC + c] + al[cp] * sm_sh[cp * CC + c];
                }
                Afsh[c] = A;
            }
        }
        if (tid == 0) {
#pragma unroll
            for (int c = 0; c < CC; ++c) {
                float f = sm_sh[222 + c] + sm_sh[216 + c];
                for (int cp = 0; cp < CC; ++cp)
                    f += cb_sh[cp] * sm_sh[108 + cp * CC + c] + gam[cp] * sm_sh[cp * CC + c];
                cfsh[c] = f;
            }
        }
    }
    __syncthreads();
    // ---- write out[b,i,:,:]: 768 floats = 192 float4 lanes
    if (tid < (LL * CC) / 4) {
        int r = tid * 4;
        float4 o;
        float* op = &o.x;
#pragma unroll
        for (int k = 0; k < 4; ++k) {
            int idx = r + k;
            int c = idx % CC, j = idx / CC;
            op[k] = Afsh[c] + Bfsh[j][c] + cfsh[c];
        }
        *(float4*)(out + ((size_t)(b * LL + i)) * (LL * CC) + r) = o;
    }
}

// ---------------------------------------------------------------------------
extern "C" void kernel_launch(void* const* d_in, const int* in_sizes, int n_in,
                              void* d_out, int out_size, void* d_ws, size_t ws_size,
                              hipStream_t stream) {
    const float* hidden = (const float*)d_in[0];          // (2,128,768)
    const float* attention_mask = (const float*)d_in[1];  // (2,128)
    const float* cls_w = (const float*)d_in[2];           // (1536,6)
    const float* cls_b = (const float*)d_in[3];           // (6,)
    const float* feat_w = (const float*)d_in[4];          // (1554,1536)
    const float* feat_b = (const float*)d_in[5];          // (1536,)
    // d_in[6] = nhops, fixed at 2
    float* out = (float*)d_out;
    float* ws = (float*)d_ws;

    k1_wfc_dots<<<H2 + 114, 256, 0, stream>>>(feat_w, cls_w, cls_b, feat_b, ws);
    k2_wfwfc_dots_tok<<<H2 + 114 + NTOK, 256, 0, stream>>>(feat_w, cls_w, feat_b, hidden, ws);
    k3_tok_s<<<NTOK, 256, 0, stream>>>(hidden, ws);
    k4_plane_out<<<NTOK, 256, 0, stream>>>(attention_mask, cls_b, ws, out);
}